// Round 1
// baseline (79.012 us; speedup 1.0000x reference)
//
#include <hip/hip_runtime.h>
#include <stdint.h>

#define B_ 128
#define Q_ 2048
#define C_ 8
#define L_ 256
#define K_ 64
#define S_ 1985            // Q - K + 1
#define KC_ 512            // K*C
#define BM_ 128            // windows per block tile
#define NTILES_ 16         // ceil over 2048 window starts

typedef short s16x8 __attribute__((ext_vector_type(8)));
typedef float f32x16 __attribute__((ext_vector_type(16)));

__device__ __forceinline__ unsigned short f2bf(float f) {
    unsigned u = __float_as_uint(f);
    u += 0x7FFFu + ((u >> 16) & 1u);        // round-to-nearest-even
    return (unsigned short)(u >> 16);
}
// monotone float -> unsigned encoding (order-preserving), for atomicMin
__device__ __forceinline__ unsigned fenc(float f) {
    unsigned u = __float_as_uint(f);
    return (u & 0x80000000u) ? ~u : (u | 0x80000000u);
}
__device__ __forceinline__ float fdec(unsigned k) {
    unsigned u = (k & 0x80000000u) ? (k ^ 0x80000000u) : ~k;
    return __uint_as_float(u);
}
__device__ __forceinline__ void async_copy16(void* lds_dst, const void* g_src) {
    __builtin_amdgcn_global_load_lds(
        (const __attribute__((address_space(1))) void*)g_src,
        (__attribute__((address_space(3))) void*)lds_dst, 16, 0, 0);
}

// ---- prep: cast ts f32 -> bf16 (contiguous [B][Q][C]) ----
__global__ __launch_bounds__(256) void k_cast_ts(const float* __restrict__ ts,
                                                 uint4* __restrict__ out) {
    int i = blockIdx.x * 256 + threadIdx.x;          // 262144 total, exact
    const float4* p = (const float4*)ts + (size_t)i * 2;
    float4 x = p[0], y = p[1];
    union { unsigned short h[8]; uint4 v; } u;
    u.h[0] = f2bf(x.x); u.h[1] = f2bf(x.y); u.h[2] = f2bf(x.z); u.h[3] = f2bf(x.w);
    u.h[4] = f2bf(y.x); u.h[5] = f2bf(y.y); u.h[6] = f2bf(y.z); u.h[7] = f2bf(y.w);
    out[i] = u.v;
}

// ---- prep: shapelets f32 -> bf16 [L][512] + sh_sq (f32) ----
__global__ __launch_bounds__(64) void k_prep_sh(const float* __restrict__ sh,
                                                uint4* __restrict__ shb,
                                                float* __restrict__ shsq) {
    const int l = blockIdx.x;
    const int t = threadIdx.x;                        // 64
    const float4* p = (const float4*)(sh + (size_t)l * KC_) + t * 2;
    float4 x = p[0], y = p[1];
    union { unsigned short h[8]; uint4 v; } u;
    u.h[0] = f2bf(x.x); u.h[1] = f2bf(x.y); u.h[2] = f2bf(x.z); u.h[3] = f2bf(x.w);
    u.h[4] = f2bf(y.x); u.h[5] = f2bf(y.y); u.h[6] = f2bf(y.z); u.h[7] = f2bf(y.w);
    shb[l * 64 + t] = u.v;
    float ss = x.x*x.x + x.y*x.y + x.z*x.z + x.w*x.w
             + y.x*y.x + y.y*y.y + y.z*y.z + y.w*y.w;
    #pragma unroll
    for (int off = 32; off >= 1; off >>= 1) ss += __shfl_down(ss, off, 64);
    if (t == 0) shsq[l] = ss;
}

// ---- init running-min buffer to "+inf" key ----
__global__ __launch_bounds__(256) void k_init(unsigned* __restrict__ hmin) {
    hmin[blockIdx.x * 256 + threadIdx.x] = 0xFFFFFFFFu;
}

// ---- main: implicit-GEMM conv + fused min-pool ----
// block: 512 thr (8 waves, 2x4), tile BM_=128 windows x all 256 shapelets
__global__ __launch_bounds__(512, 4) void k_main(
    const float* __restrict__ ts,         // f32 [B][Q][C]
    const uint4* __restrict__ tsb,        // bf16 [B][Q][C], 1 uint4 per q-row
    const char*  __restrict__ shb,        // bf16 [L][512] bytes
    const float* __restrict__ shsq,       // [L]
    unsigned*    __restrict__ hmin)       // [B][L] encoded min
{
    __shared__ uint4 a_lds4[192];         // 192 ts-rows x 8ch bf16 = 3 KB
    __shared__ uint4 b_lds4[2][2048];     // 2 x (256 cols x 64k bf16) = 64 KB
    __shared__ float rsq[192];
    __shared__ float wq[BM_];

    const int tile = blockIdx.x;
    const int b    = blockIdx.y;
    const int s0   = tile * BM_;
    const int tid  = threadIdx.x;
    const int lane = tid & 63;
    const int wv   = tid >> 6;
    const int wm   = wv >> 2;             // 0..1  (row group of 64)
    const int wn   = wv & 3;              // 0..3  (col group of 64)
    const int l31  = lane & 31;
    const int hi   = lane >> 5;

    // issue B stage 0 (async, swizzled source -> linear LDS dest)
    {
        const int cg = lane >> 3, j = lane & 7;
        #pragma unroll
        for (int it = 0; it < 4; ++it) {
            int colbase = wv * 32 + it * 8;
            int col = colbase + cg;
            const char* g = shb + (size_t)col * 1024 + ((j ^ (col & 7)) << 4);
            async_copy16((char*)b_lds4[0] + colbase * 128, g);
        }
    }

    // stage A tile (bf16) + per-row sum of squares (f32, exact path)
    if (tid < 192) {
        int row = s0 + tid;
        uint4 v; v.x = v.y = v.z = v.w = 0u;
        float r = 0.f;
        if (row < Q_) {
            v = tsb[(size_t)b * Q_ + row];
            const float4* pf = (const float4*)(ts + ((size_t)b * Q_ + row) * C_);
            float4 x = pf[0], y = pf[1];
            r = x.x*x.x + x.y*x.y + x.z*x.z + x.w*x.w
              + y.x*y.x + y.y*y.y + y.z*y.z + y.w*y.w;
        }
        a_lds4[tid] = v;
        rsq[tid] = r;
    }
    __syncthreads();   // A staged, rsq ready, B0 landed (vmcnt drained)

    if (tid < BM_) {
        float s = 0.f;
        #pragma unroll 16
        for (int k = 0; k < K_; ++k) s += rsq[tid + k];
        wq[tid] = s;                      // read only after later barriers
    }

    const f32x16 fz = {0.f,0.f,0.f,0.f,0.f,0.f,0.f,0.f,
                       0.f,0.f,0.f,0.f,0.f,0.f,0.f,0.f};
    f32x16 acc00 = fz, acc01 = fz, acc10 = fz, acc11 = fz;

    const char* ab   = (const char*)a_lds4;
    const int   arow = wm * 64 + l31 + hi;       // ts-row index base
    const int   bc0  = (wn * 64 + l31) * 128;    // byte base of B col
    const int   cswz = l31 & 7;

    for (int st = 0; st < 8; ++st) {
        if (st < 7) {                     // prefetch next 64-k chunk
            const int cg = lane >> 3, j = lane & 7;
            char* bufb = (char*)b_lds4[(st + 1) & 1];
            #pragma unroll
            for (int it = 0; it < 4; ++it) {
                int colbase = wv * 32 + it * 8;
                int col = colbase + cg;
                const char* g = shb + (size_t)col * 1024 + (st + 1) * 128
                              + ((j ^ (col & 7)) << 4);
                async_copy16(bufb + colbase * 128, g);
            }
        }
        const char* bb = (const char*)b_lds4[st & 1];
        #pragma unroll
        for (int ks = 0; ks < 4; ++ks) {
            int aoff = (arow + st * 8 + ks * 2) * 16;
            s16x8 a0 = *(const s16x8*)(ab + aoff);
            s16x8 a1 = *(const s16x8*)(ab + aoff + 512);       // +32 rows
            int slot = ((ks * 2 + hi) ^ cswz) << 4;
            s16x8 b0 = *(const s16x8*)(bb + bc0 + slot);
            s16x8 b1 = *(const s16x8*)(bb + bc0 + 4096 + slot); // +32 cols
            acc00 = __builtin_amdgcn_mfma_f32_32x32x16_bf16(a0, b0, acc00, 0, 0, 0);
            acc01 = __builtin_amdgcn_mfma_f32_32x32x16_bf16(a0, b1, acc01, 0, 0, 0);
            acc10 = __builtin_amdgcn_mfma_f32_32x32x16_bf16(a1, b0, acc10, 0, 0, 0);
            acc11 = __builtin_amdgcn_mfma_f32_32x32x16_bf16(a1, b1, acc11, 0, 0, 0);
        }
        __syncthreads();
    }

    // epilogue: dist = (wq - 2*cross + shsq)/512, min over valid rows
    const int col0 = wn * 64 + l31;
    const int col1 = col0 + 32;
    float m0 = __builtin_inff();
    float m1 = __builtin_inff();
    {
        int rb = wm * 64 + 4 * hi;
        #pragma unroll
        for (int r = 0; r < 16; ++r) {
            int row = rb + (r & 3) + 8 * (r >> 2);
            if (s0 + row < S_) {
                float w = wq[row];
                m0 = fminf(m0, w - 2.f * acc00[r]);
                m1 = fminf(m1, w - 2.f * acc01[r]);
            }
        }
        rb += 32;
        #pragma unroll
        for (int r = 0; r < 16; ++r) {
            int row = rb + (r & 3) + 8 * (r >> 2);
            if (s0 + row < S_) {
                float w = wq[row];
                m0 = fminf(m0, w - 2.f * acc10[r]);
                m1 = fminf(m1, w - 2.f * acc11[r]);
            }
        }
    }
    // + shsq commutes with min (constant per column)
    m0 = (m0 + shsq[col0]) * (1.f / 512.f);
    m1 = (m1 + shsq[col1]) * (1.f / 512.f);
    m0 = fminf(m0, __shfl_xor(m0, 32, 64));
    m1 = fminf(m1, __shfl_xor(m1, 32, 64));
    if (hi == 0) {
        atomicMin(&hmin[b * L_ + col0], fenc(m0));
        atomicMin(&hmin[b * L_ + col1], fenc(m1));
    }
}

// ---- final: gating + FC [B,L] -> [B,2] ----
__global__ __launch_bounds__(256) void k_final(const unsigned* __restrict__ hmin,
                                               const float* __restrict__ gating,
                                               const float* __restrict__ w,
                                               const float* __restrict__ bias,
                                               float* __restrict__ out) {
    const int b = blockIdx.x, t = threadIdx.x;       // 256 threads = L
    float v = fdec(hmin[b * L_ + t]);
    float g = 1.f / (1.f + __expf(-gating[t]));
    float mg = v * g;
    float p0 = mg * w[t];
    float p1 = mg * w[L_ + t];
    #pragma unroll
    for (int off = 32; off >= 1; off >>= 1) {
        p0 += __shfl_down(p0, off, 64);
        p1 += __shfl_down(p1, off, 64);
    }
    __shared__ float r0[4], r1[4];
    int wvi = t >> 6, ln = t & 63;
    if (ln == 0) { r0[wvi] = p0; r1[wvi] = p1; }
    __syncthreads();
    if (t == 0) {
        out[b * 2 + 0] = r0[0] + r0[1] + r0[2] + r0[3] + bias[0];
        out[b * 2 + 1] = r1[0] + r1[1] + r1[2] + r1[3] + bias[1];
    }
}

extern "C" void kernel_launch(void* const* d_in, const int* in_sizes, int n_in,
                              void* d_out, int out_size, void* d_ws, size_t ws_size,
                              hipStream_t stream) {
    const float* ts     = (const float*)d_in[0];
    const float* sh     = (const float*)d_in[1];
    const float* gating = (const float*)d_in[2];
    const float* fw     = (const float*)d_in[3];
    const float* fb     = (const float*)d_in[4];
    float* out = (float*)d_out;

    char* ws = (char*)d_ws;
    uint4*    tsb  = (uint4*)ws;                               // 4 MiB
    char*     shb  = ws + 4194304;                             // 256 KiB
    float*    shsq = (float*)(ws + 4194304 + 262144);          // 1 KiB
    unsigned* hmin = (unsigned*)(ws + 4194304 + 262144 + 1024);// 128 KiB

    k_cast_ts<<<1024, 256, 0, stream>>>(ts, tsb);
    k_prep_sh<<<256, 64, 0, stream>>>(sh, (uint4*)shb, shsq);
    k_init<<<128, 256, 0, stream>>>(hmin);
    dim3 grid(NTILES_, B_);
    k_main<<<grid, 512, 0, stream>>>(ts, tsb, shb, shsq, hmin);
    k_final<<<128, 256, 0, stream>>>(hmin, gating, fw, fb, out);
}

// Round 3
// 76.600 us; speedup vs baseline: 1.0315x; 1.0315x over previous
//
#include <hip/hip_runtime.h>
#include <stdint.h>

#define B_ 128
#define Q_ 2048
#define C_ 8
#define L_ 256
#define K_ 64
#define S_ 1985            // Q - K + 1
#define KC_ 512            // K*C
#define BM_ 128            // windows per block tile
#define NTILES_ 16         // ceil over 2048 window starts

typedef short s16x8 __attribute__((ext_vector_type(8)));
typedef float f32x16 __attribute__((ext_vector_type(16)));

__device__ __forceinline__ unsigned short f2bf(float f) {
    unsigned u = __float_as_uint(f);
    u += 0x7FFFu + ((u >> 16) & 1u);        // round-to-nearest-even
    return (unsigned short)(u >> 16);
}
// monotone float -> unsigned encoding (order-preserving), for atomicMin
__device__ __forceinline__ unsigned fenc(float f) {
    unsigned u = __float_as_uint(f);
    return (u & 0x80000000u) ? ~u : (u | 0x80000000u);
}
__device__ __forceinline__ float fdec(unsigned k) {
    unsigned u = (k & 0x80000000u) ? (k ^ 0x80000000u) : ~k;
    return __uint_as_float(u);
}
__device__ __forceinline__ void async_copy16(void* lds_dst, const void* g_src) {
    __builtin_amdgcn_global_load_lds(
        (const __attribute__((address_space(1))) void*)g_src,
        (__attribute__((address_space(3))) void*)lds_dst, 16, 0, 0);
}

// ---- prep: cast ts f32 -> bf16 (contiguous [B][Q][C]) ----
__global__ __launch_bounds__(256) void k_cast_ts(const float* __restrict__ ts,
                                                 uint4* __restrict__ out) {
    int i = blockIdx.x * 256 + threadIdx.x;          // 262144 total, exact
    const float4* p = (const float4*)ts + (size_t)i * 2;
    float4 x = p[0], y = p[1];
    union { unsigned short h[8]; uint4 v; } u;
    u.h[0] = f2bf(x.x); u.h[1] = f2bf(x.y); u.h[2] = f2bf(x.z); u.h[3] = f2bf(x.w);
    u.h[4] = f2bf(y.x); u.h[5] = f2bf(y.y); u.h[6] = f2bf(y.z); u.h[7] = f2bf(y.w);
    out[i] = u.v;
}

// ---- prep: shapelets f32 -> bf16 [L][512] + sh_sq (f32) ----
__global__ __launch_bounds__(64) void k_prep_sh(const float* __restrict__ sh,
                                                uint4* __restrict__ shb,
                                                float* __restrict__ shsq) {
    const int l = blockIdx.x;
    const int t = threadIdx.x;                        // 64
    const float4* p = (const float4*)(sh + (size_t)l * KC_) + t * 2;
    float4 x = p[0], y = p[1];
    union { unsigned short h[8]; uint4 v; } u;
    u.h[0] = f2bf(x.x); u.h[1] = f2bf(x.y); u.h[2] = f2bf(x.z); u.h[3] = f2bf(x.w);
    u.h[4] = f2bf(y.x); u.h[5] = f2bf(y.y); u.h[6] = f2bf(y.z); u.h[7] = f2bf(y.w);
    shb[l * 64 + t] = u.v;
    float ss = x.x*x.x + x.y*x.y + x.z*x.z + x.w*x.w
             + y.x*y.x + y.y*y.y + y.z*y.z + y.w*y.w;
    #pragma unroll
    for (int off = 32; off >= 1; off >>= 1) ss += __shfl_down(ss, off, 64);
    if (t == 0) shsq[l] = ss;
}

// ---- init running-min buffer to "+inf" key ----
__global__ __launch_bounds__(256) void k_init(unsigned* __restrict__ hmin) {
    hmin[blockIdx.x * 256 + threadIdx.x] = 0xFFFFFFFFu;
}

// ---- main: implicit-GEMM conv + fused min-pool ----
// block: 256 thr (4 waves as 2m x 2n), tile BM_=128 windows x 256 shapelets
// wave tile: 64 rows x 128 cols -> acc 2x4 of 32x32 (128 acc regs)
__global__ __launch_bounds__(256, 2) void k_main(
    const float* __restrict__ ts,         // f32 [B][Q][C]
    const uint4* __restrict__ tsb,        // bf16 [B][Q][C], 1 uint4 per q-row
    const char*  __restrict__ shb,        // bf16 [L][512] bytes
    const float* __restrict__ shsq,       // [L]
    unsigned*    __restrict__ hmin)       // [B][L] encoded min
{
    __shared__ uint4 a_lds4[192];         // 192 ts-rows x 8ch bf16 = 3 KB
    __shared__ uint4 b_lds4[2][2048];     // 2 x (256 cols x 64k bf16) = 64 KB
    __shared__ float rsq[192];
    __shared__ float wq[BM_];

    const int tile = blockIdx.x;
    const int b    = blockIdx.y;
    const int s0   = tile * BM_;
    const int tid  = threadIdx.x;
    const int lane = tid & 63;
    const int wv   = tid >> 6;            // 0..3
    const int l31  = lane & 31;
    const int hi   = lane >> 5;
    const int wmm  = wv >> 1;             // 0..1 (row group of 64)
    const int wnn  = wv & 1;              // 0..1 (col group of 128)

    // issue B stage 0 (async, swizzled source -> linear LDS dest)
    // 2048 x 16B copies over 256 threads = 8 each
    {
        const int cg = lane >> 3, j = lane & 7;
        #pragma unroll
        for (int it = 0; it < 8; ++it) {
            int colbase = wv * 64 + it * 8;
            int col = colbase + cg;
            const char* g = shb + (size_t)col * 1024 + ((j ^ (col & 7)) << 4);
            async_copy16((char*)b_lds4[0] + colbase * 128, g);
        }
    }

    // stage A tile (bf16) + per-row sum of squares (f32, exact path)
    if (tid < 192) {
        int row = s0 + tid;
        uint4 v; v.x = v.y = v.z = v.w = 0u;
        float r = 0.f;
        if (row < Q_) {
            v = tsb[(size_t)b * Q_ + row];
            const float4* pf = (const float4*)(ts + ((size_t)b * Q_ + row) * C_);
            float4 x = pf[0], y = pf[1];
            r = x.x*x.x + x.y*x.y + x.z*x.z + x.w*x.w
              + y.x*y.x + y.y*y.y + y.z*y.z + y.w*y.w;
        }
        a_lds4[tid] = v;
        rsq[tid] = r;
    }
    __syncthreads();   // A staged, rsq ready, B0 landed (vmcnt drained)

    if (tid < BM_) {
        float s = 0.f;
        #pragma unroll 16
        for (int k = 0; k < K_; ++k) s += rsq[tid + k];
        wq[tid] = s;                      // read only after later barriers
    }

    const f32x16 fz = {0.f,0.f,0.f,0.f,0.f,0.f,0.f,0.f,
                       0.f,0.f,0.f,0.f,0.f,0.f,0.f,0.f};
    f32x16 acc00 = fz, acc01 = fz, acc02 = fz, acc03 = fz;
    f32x16 acc10 = fz, acc11 = fz, acc12 = fz, acc13 = fz;

    const char* ab   = (const char*)a_lds4;
    const int   arow = wmm * 64 + l31 + hi;        // ts-row index base
    const int   bc0  = (wnn * 128 + l31) * 128;    // byte base of B col
    const int   cswz = l31 & 7;

    for (int st = 0; st < 8; ++st) {
        if (st < 7) {                     // prefetch next 64-k chunk
            const int cg = lane >> 3, j = lane & 7;
            char* bufb = (char*)b_lds4[(st + 1) & 1];
            #pragma unroll
            for (int it = 0; it < 8; ++it) {
                int colbase = wv * 64 + it * 8;
                int col = colbase + cg;
                const char* g = shb + (size_t)col * 1024 + (st + 1) * 128
                              + ((j ^ (col & 7)) << 4);
                async_copy16(bufb + colbase * 128, g);
            }
        }
        const char* bb = (const char*)b_lds4[st & 1];
        #pragma unroll
        for (int ks = 0; ks < 4; ++ks) {
            int aoff = (arow + st * 8 + ks * 2) * 16;
            s16x8 a0 = *(const s16x8*)(ab + aoff);
            s16x8 a1 = *(const s16x8*)(ab + aoff + 512);        // +32 rows
            int slot = ((ks * 2 + hi) ^ cswz) << 4;
            const char* bp = bb + bc0 + slot;
            s16x8 b0 = *(const s16x8*)(bp);
            s16x8 b1 = *(const s16x8*)(bp + 32 * 128);
            s16x8 b2 = *(const s16x8*)(bp + 64 * 128);
            s16x8 b3 = *(const s16x8*)(bp + 96 * 128);
            acc00 = __builtin_amdgcn_mfma_f32_32x32x16_bf16(a0, b0, acc00, 0, 0, 0);
            acc01 = __builtin_amdgcn_mfma_f32_32x32x16_bf16(a0, b1, acc01, 0, 0, 0);
            acc02 = __builtin_amdgcn_mfma_f32_32x32x16_bf16(a0, b2, acc02, 0, 0, 0);
            acc03 = __builtin_amdgcn_mfma_f32_32x32x16_bf16(a0, b3, acc03, 0, 0, 0);
            acc10 = __builtin_amdgcn_mfma_f32_32x32x16_bf16(a1, b0, acc10, 0, 0, 0);
            acc11 = __builtin_amdgcn_mfma_f32_32x32x16_bf16(a1, b1, acc11, 0, 0, 0);
            acc12 = __builtin_amdgcn_mfma_f32_32x32x16_bf16(a1, b2, acc12, 0, 0, 0);
            acc13 = __builtin_amdgcn_mfma_f32_32x32x16_bf16(a1, b3, acc13, 0, 0, 0);
        }
        __syncthreads();
    }

    // epilogue: dist = (wq - 2*cross + shsq)/512, min over valid rows
    const float inf = __builtin_inff();
    float m0 = inf, m1 = inf, m2 = inf, m3 = inf;
    {
        int rb = wmm * 64 + 4 * hi;
        #pragma unroll
        for (int r = 0; r < 16; ++r) {
            int row = rb + (r & 3) + 8 * (r >> 2);
            float w = (s0 + row < S_) ? wq[row] : inf;
            m0 = fminf(m0, w - 2.f * acc00[r]);
            m1 = fminf(m1, w - 2.f * acc01[r]);
            m2 = fminf(m2, w - 2.f * acc02[r]);
            m3 = fminf(m3, w - 2.f * acc03[r]);
        }
        rb += 32;
        #pragma unroll
        for (int r = 0; r < 16; ++r) {
            int row = rb + (r & 3) + 8 * (r >> 2);
            float w = (s0 + row < S_) ? wq[row] : inf;
            m0 = fminf(m0, w - 2.f * acc10[r]);
            m1 = fminf(m1, w - 2.f * acc11[r]);
            m2 = fminf(m2, w - 2.f * acc12[r]);
            m3 = fminf(m3, w - 2.f * acc13[r]);
        }
    }
    // + shsq commutes with min (constant per column)
    const int col0 = wnn * 128 + l31;
    m0 = (m0 + shsq[col0])      * (1.f / 512.f);
    m1 = (m1 + shsq[col0 + 32]) * (1.f / 512.f);
    m2 = (m2 + shsq[col0 + 64]) * (1.f / 512.f);
    m3 = (m3 + shsq[col0 + 96]) * (1.f / 512.f);
    m0 = fminf(m0, __shfl_xor(m0, 32, 64));
    m1 = fminf(m1, __shfl_xor(m1, 32, 64));
    m2 = fminf(m2, __shfl_xor(m2, 32, 64));
    m3 = fminf(m3, __shfl_xor(m3, 32, 64));
    if (hi == 0) {
        atomicMin(&hmin[b * L_ + col0],      fenc(m0));
        atomicMin(&hmin[b * L_ + col0 + 32], fenc(m1));
        atomicMin(&hmin[b * L_ + col0 + 64], fenc(m2));
        atomicMin(&hmin[b * L_ + col0 + 96], fenc(m3));
    }
}

// ---- final: gating + FC [B,L] -> [B,2] ----
__global__ __launch_bounds__(256) void k_final(const unsigned* __restrict__ hmin,
                                               const float* __restrict__ gating,
                                               const float* __restrict__ w,
                                               const float* __restrict__ bias,
                                               float* __restrict__ out) {
    const int b = blockIdx.x, t = threadIdx.x;       // 256 threads = L
    float v = fdec(hmin[b * L_ + t]);
    float g = 1.f / (1.f + __expf(-gating[t]));
    float mg = v * g;
    float p0 = mg * w[t];
    float p1 = mg * w[L_ + t];
    #pragma unroll
    for (int off = 32; off >= 1; off >>= 1) {
        p0 += __shfl_down(p0, off, 64);
        p1 += __shfl_down(p1, off, 64);
    }
    __shared__ float r0[4], r1[4];
    int wvi = t >> 6, ln = t & 63;
    if (ln == 0) { r0[wvi] = p0; r1[wvi] = p1; }
    __syncthreads();
    if (t == 0) {
        out[b * 2 + 0] = r0[0] + r0[1] + r0[2] + r0[3] + bias[0];
        out[b * 2 + 1] = r1[0] + r1[1] + r1[2] + r1[3] + bias[1];
    }
}

extern "C" void kernel_launch(void* const* d_in, const int* in_sizes, int n_in,
                              void* d_out, int out_size, void* d_ws, size_t ws_size,
                              hipStream_t stream) {
    const float* ts     = (const float*)d_in[0];
    const float* sh     = (const float*)d_in[1];
    const float* gating = (const float*)d_in[2];
    const float* fw     = (const float*)d_in[3];
    const float* fb     = (const float*)d_in[4];
    float* out = (float*)d_out;

    char* ws = (char*)d_ws;
    uint4*    tsb  = (uint4*)ws;                               // 4 MiB
    char*     shb  = ws + 4194304;                             // 256 KiB
    float*    shsq = (float*)(ws + 4194304 + 262144);          // 1 KiB
    unsigned* hmin = (unsigned*)(ws + 4194304 + 262144 + 1024);// 128 KiB

    k_cast_ts<<<1024, 256, 0, stream>>>(ts, tsb);
    k_prep_sh<<<256, 64, 0, stream>>>(sh, (uint4*)shb, shsq);
    k_init<<<128, 256, 0, stream>>>(hmin);
    dim3 grid(NTILES_, B_);
    k_main<<<grid, 256, 0, stream>>>(ts, tsb, shb, shsq, hmin);
    k_final<<<128, 256, 0, stream>>>(hmin, gating, fw, fb, out);
}

// Round 4
// 76.410 us; speedup vs baseline: 1.0341x; 1.0025x over previous
//
#include <hip/hip_runtime.h>
#include <stdint.h>

#define B_ 128
#define Q_ 2048
#define C_ 8
#define L_ 256
#define K_ 64
#define S_ 1985            // Q - K + 1
#define KC_ 512            // K*C
#define BM_ 128            // windows per block tile
#define NTILES_ 16         // ceil over 2048 window starts

typedef short s16x8 __attribute__((ext_vector_type(8)));
typedef float f32x16 __attribute__((ext_vector_type(16)));

__device__ __forceinline__ unsigned short f2bf(float f) {
    unsigned u = __float_as_uint(f);
    u += 0x7FFFu + ((u >> 16) & 1u);        // round-to-nearest-even
    return (unsigned short)(u >> 16);
}
// monotone float -> unsigned encoding (order-preserving), for atomicMin
__device__ __forceinline__ unsigned fenc(float f) {
    unsigned u = __float_as_uint(f);
    return (u & 0x80000000u) ? ~u : (u | 0x80000000u);
}
__device__ __forceinline__ float fdec(unsigned k) {
    unsigned u = (k & 0x80000000u) ? (k ^ 0x80000000u) : ~k;
    return __uint_as_float(u);
}
__device__ __forceinline__ void async_copy16(void* lds_dst, const void* g_src) {
    __builtin_amdgcn_global_load_lds(
        (const __attribute__((address_space(1))) void*)g_src,
        (__attribute__((address_space(3))) void*)lds_dst, 16, 0, 0);
}

// ---- prep: cast ts f32 -> bf16 (contiguous [B][Q][C]) ----
__global__ __launch_bounds__(256) void k_cast_ts(const float* __restrict__ ts,
                                                 uint4* __restrict__ out) {
    int i = blockIdx.x * 256 + threadIdx.x;          // 262144 total, exact
    const float4* p = (const float4*)ts + (size_t)i * 2;
    float4 x = p[0], y = p[1];
    union { unsigned short h[8]; uint4 v; } u;
    u.h[0] = f2bf(x.x); u.h[1] = f2bf(x.y); u.h[2] = f2bf(x.z); u.h[3] = f2bf(x.w);
    u.h[4] = f2bf(y.x); u.h[5] = f2bf(y.y); u.h[6] = f2bf(y.z); u.h[7] = f2bf(y.w);
    out[i] = u.v;
}

// ---- prep: shapelets f32 -> bf16 [L][512] + sh_sq (f32) ----
__global__ __launch_bounds__(64) void k_prep_sh(const float* __restrict__ sh,
                                                uint4* __restrict__ shb,
                                                float* __restrict__ shsq) {
    const int l = blockIdx.x;
    const int t = threadIdx.x;                        // 64
    const float4* p = (const float4*)(sh + (size_t)l * KC_) + t * 2;
    float4 x = p[0], y = p[1];
    union { unsigned short h[8]; uint4 v; } u;
    u.h[0] = f2bf(x.x); u.h[1] = f2bf(x.y); u.h[2] = f2bf(x.z); u.h[3] = f2bf(x.w);
    u.h[4] = f2bf(y.x); u.h[5] = f2bf(y.y); u.h[6] = f2bf(y.z); u.h[7] = f2bf(y.w);
    shb[l * 64 + t] = u.v;
    float ss = x.x*x.x + x.y*x.y + x.z*x.z + x.w*x.w
             + y.x*y.x + y.y*y.y + y.z*y.z + y.w*y.w;
    #pragma unroll
    for (int off = 32; off >= 1; off >>= 1) ss += __shfl_down(ss, off, 64);
    if (t == 0) shsq[l] = ss;
}

// ---- init running-min buffer to "+inf" key ----
__global__ __launch_bounds__(256) void k_init(unsigned* __restrict__ hmin) {
    hmin[blockIdx.x * 256 + threadIdx.x] = 0xFFFFFFFFu;
}

// ---- main: implicit-GEMM conv + fused min-pool ----
// block: 256 thr (4 waves as 2m x 2n), tile BM_=128 windows x 256 shapelets
// wave tile: 64 rows x 128 cols -> acc 2x4 of 32x32 (128 acc regs)
// B LDS swizzle: chunk f = k2 ^ ((col>>2)&7) -> bank-quad 8*(col%4) + f is a
// bijection over the 32 lanes of a half-wave => conflict-free ds_read_b128.
__global__ __launch_bounds__(256, 2) void k_main(
    const float* __restrict__ ts,         // f32 [B][Q][C]
    const uint4* __restrict__ tsb,        // bf16 [B][Q][C], 1 uint4 per q-row
    const char*  __restrict__ shb,        // bf16 [L][512] bytes
    const float* __restrict__ shsq,       // [L]
    unsigned*    __restrict__ hmin)       // [B][L] encoded min
{
    __shared__ uint4 a_lds4[192];         // 192 ts-rows x 8ch bf16 = 3 KB
    __shared__ uint4 b_lds4[2][2048];     // 2 x (256 cols x 64k bf16) = 64 KB
    __shared__ float rsq[192];
    __shared__ float wq[BM_];

    const int tile = blockIdx.x;
    const int b    = blockIdx.y;
    const int s0   = tile * BM_;
    const int tid  = threadIdx.x;
    const int lane = tid & 63;
    const int wv   = tid >> 6;            // 0..3
    const int l31  = lane & 31;
    const int hi   = lane >> 5;
    const int wmm  = wv >> 1;             // 0..1 (row group of 64)
    const int wnn  = wv & 1;              // 0..1 (col group of 128)

    // issue B stage 0 (async, swizzled source -> linear LDS dest)
    // 2048 x 16B copies over 256 threads = 8 each
    {
        const int cg = lane >> 3, j = lane & 7;
        #pragma unroll
        for (int it = 0; it < 8; ++it) {
            int colbase = wv * 64 + it * 8;
            int col = colbase + cg;
            const char* g = shb + (size_t)col * 1024 + ((j ^ ((col >> 2) & 7)) << 4);
            async_copy16((char*)b_lds4[0] + colbase * 128, g);
        }
    }

    // stage A tile (bf16) + per-row sum of squares (f32, exact path)
    if (tid < 192) {
        int row = s0 + tid;
        uint4 v; v.x = v.y = v.z = v.w = 0u;
        float r = 0.f;
        if (row < Q_) {
            v = tsb[(size_t)b * Q_ + row];
            const float4* pf = (const float4*)(ts + ((size_t)b * Q_ + row) * C_);
            float4 x = pf[0], y = pf[1];
            r = x.x*x.x + x.y*x.y + x.z*x.z + x.w*x.w
              + y.x*y.x + y.y*y.y + y.z*y.z + y.w*y.w;
        }
        a_lds4[tid] = v;
        rsq[tid] = r;
    }
    __syncthreads();   // A staged, rsq ready, B0 landed (vmcnt drained)

    if (tid < BM_) {
        float s = 0.f;
        #pragma unroll 16
        for (int k = 0; k < K_; ++k) s += rsq[tid + k];
        wq[tid] = s;                      // read only after later barriers
    }

    const f32x16 fz = {0.f,0.f,0.f,0.f,0.f,0.f,0.f,0.f,
                       0.f,0.f,0.f,0.f,0.f,0.f,0.f,0.f};
    f32x16 acc00 = fz, acc01 = fz, acc02 = fz, acc03 = fz;
    f32x16 acc10 = fz, acc11 = fz, acc12 = fz, acc13 = fz;

    const char* ab   = (const char*)a_lds4;
    const int   arow = wmm * 64 + l31 + hi;        // ts-row index base
    const int   bc0  = (wnn * 128 + l31) * 128;    // byte base of B col
    const int   cswz = (l31 >> 2) & 7;             // bank-spread swizzle

    for (int st = 0; st < 8; ++st) {
        if (st < 7) {                     // prefetch next 64-k chunk
            const int cg = lane >> 3, j = lane & 7;
            char* bufb = (char*)b_lds4[(st + 1) & 1];
            #pragma unroll
            for (int it = 0; it < 8; ++it) {
                int colbase = wv * 64 + it * 8;
                int col = colbase + cg;
                const char* g = shb + (size_t)col * 1024 + (st + 1) * 128
                              + ((j ^ ((col >> 2) & 7)) << 4);
                async_copy16(bufb + colbase * 128, g);
            }
        }
        const char* bb = (const char*)b_lds4[st & 1];
        #pragma unroll
        for (int ks = 0; ks < 4; ++ks) {
            int aoff = (arow + st * 8 + ks * 2) * 16;
            s16x8 a0 = *(const s16x8*)(ab + aoff);
            s16x8 a1 = *(const s16x8*)(ab + aoff + 512);        // +32 rows
            int slot = ((ks * 2 + hi) ^ cswz) << 4;
            const char* bp = bb + bc0 + slot;
            s16x8 b0 = *(const s16x8*)(bp);
            s16x8 b1 = *(const s16x8*)(bp + 32 * 128);
            s16x8 b2 = *(const s16x8*)(bp + 64 * 128);
            s16x8 b3 = *(const s16x8*)(bp + 96 * 128);
            acc00 = __builtin_amdgcn_mfma_f32_32x32x16_bf16(a0, b0, acc00, 0, 0, 0);
            acc01 = __builtin_amdgcn_mfma_f32_32x32x16_bf16(a0, b1, acc01, 0, 0, 0);
            acc02 = __builtin_amdgcn_mfma_f32_32x32x16_bf16(a0, b2, acc02, 0, 0, 0);
            acc03 = __builtin_amdgcn_mfma_f32_32x32x16_bf16(a0, b3, acc03, 0, 0, 0);
            acc10 = __builtin_amdgcn_mfma_f32_32x32x16_bf16(a1, b0, acc10, 0, 0, 0);
            acc11 = __builtin_amdgcn_mfma_f32_32x32x16_bf16(a1, b1, acc11, 0, 0, 0);
            acc12 = __builtin_amdgcn_mfma_f32_32x32x16_bf16(a1, b2, acc12, 0, 0, 0);
            acc13 = __builtin_amdgcn_mfma_f32_32x32x16_bf16(a1, b3, acc13, 0, 0, 0);
        }
        __syncthreads();
    }

    // epilogue: dist = (wq - 2*cross + shsq)/512, min over valid rows
    const float inf = __builtin_inff();
    float m0 = inf, m1 = inf, m2 = inf, m3 = inf;
    {
        int rb = wmm * 64 + 4 * hi;
        #pragma unroll
        for (int r = 0; r < 16; ++r) {
            int row = rb + (r & 3) + 8 * (r >> 2);
            float w = (s0 + row < S_) ? wq[row] : inf;
            m0 = fminf(m0, w - 2.f * acc00[r]);
            m1 = fminf(m1, w - 2.f * acc01[r]);
            m2 = fminf(m2, w - 2.f * acc02[r]);
            m3 = fminf(m3, w - 2.f * acc03[r]);
        }
        rb += 32;
        #pragma unroll
        for (int r = 0; r < 16; ++r) {
            int row = rb + (r & 3) + 8 * (r >> 2);
            float w = (s0 + row < S_) ? wq[row] : inf;
            m0 = fminf(m0, w - 2.f * acc10[r]);
            m1 = fminf(m1, w - 2.f * acc11[r]);
            m2 = fminf(m2, w - 2.f * acc12[r]);
            m3 = fminf(m3, w - 2.f * acc13[r]);
        }
    }
    // + shsq commutes with min (constant per column)
    const int col0 = wnn * 128 + l31;
    m0 = (m0 + shsq[col0])      * (1.f / 512.f);
    m1 = (m1 + shsq[col0 + 32]) * (1.f / 512.f);
    m2 = (m2 + shsq[col0 + 64]) * (1.f / 512.f);
    m3 = (m3 + shsq[col0 + 96]) * (1.f / 512.f);
    m0 = fminf(m0, __shfl_xor(m0, 32, 64));
    m1 = fminf(m1, __shfl_xor(m1, 32, 64));
    m2 = fminf(m2, __shfl_xor(m2, 32, 64));
    m3 = fminf(m3, __shfl_xor(m3, 32, 64));
    if (hi == 0) {
        atomicMin(&hmin[b * L_ + col0],      fenc(m0));
        atomicMin(&hmin[b * L_ + col0 + 32], fenc(m1));
        atomicMin(&hmin[b * L_ + col0 + 64], fenc(m2));
        atomicMin(&hmin[b * L_ + col0 + 96], fenc(m3));
    }
}

// ---- final: gating + FC [B,L] -> [B,2] ----
__global__ __launch_bounds__(256) void k_final(const unsigned* __restrict__ hmin,
                                               const float* __restrict__ gating,
                                               const float* __restrict__ w,
                                               const float* __restrict__ bias,
                                               float* __restrict__ out) {
    const int b = blockIdx.x, t = threadIdx.x;       // 256 threads = L
    float v = fdec(hmin[b * L_ + t]);
    float g = 1.f / (1.f + __expf(-gating[t]));
    float mg = v * g;
    float p0 = mg * w[t];
    float p1 = mg * w[L_ + t];
    #pragma unroll
    for (int off = 32; off >= 1; off >>= 1) {
        p0 += __shfl_down(p0, off, 64);
        p1 += __shfl_down(p1, off, 64);
    }
    __shared__ float r0[4], r1[4];
    int wvi = t >> 6, ln = t & 63;
    if (ln == 0) { r0[wvi] = p0; r1[wvi] = p1; }
    __syncthreads();
    if (t == 0) {
        out[b * 2 + 0] = r0[0] + r0[1] + r0[2] + r0[3] + bias[0];
        out[b * 2 + 1] = r1[0] + r1[1] + r1[2] + r1[3] + bias[1];
    }
}

extern "C" void kernel_launch(void* const* d_in, const int* in_sizes, int n_in,
                              void* d_out, int out_size, void* d_ws, size_t ws_size,
                              hipStream_t stream) {
    const float* ts     = (const float*)d_in[0];
    const float* sh     = (const float*)d_in[1];
    const float* gating = (const float*)d_in[2];
    const float* fw     = (const float*)d_in[3];
    const float* fb     = (const float*)d_in[4];
    float* out = (float*)d_out;

    char* ws = (char*)d_ws;
    uint4*    tsb  = (uint4*)ws;                               // 4 MiB
    char*     shb  = ws + 4194304;                             // 256 KiB
    float*    shsq = (float*)(ws + 4194304 + 262144);          // 1 KiB
    unsigned* hmin = (unsigned*)(ws + 4194304 + 262144 + 1024);// 128 KiB

    k_cast_ts<<<1024, 256, 0, stream>>>(ts, tsb);
    k_prep_sh<<<256, 64, 0, stream>>>(sh, (uint4*)shb, shsq);
    k_init<<<128, 256, 0, stream>>>(hmin);
    dim3 grid(NTILES_, B_);
    k_main<<<grid, 256, 0, stream>>>(ts, tsb, shb, shsq, hmin);
    k_final<<<128, 256, 0, stream>>>(hmin, gating, fw, fb, out);
}